// Round 7
// baseline (259.180 us; speedup 1.0000x reference)
//
#include <hip/hip_runtime.h>
#include <stdint.h>

typedef float   f32x4  __attribute__((ext_vector_type(4)));
typedef __bf16  bf16x8 __attribute__((ext_vector_type(8)));
typedef uint32_t u32x4 __attribute__((ext_vector_type(4)));

// Round-half-up fp32->bf16 for a pair, packed into one dword: low16 = lo, high16 = hi.
__device__ __forceinline__ uint32_t pack_rnd(float lo, float hi) {
    uint32_t a = __float_as_uint(hi) + 0x8000u;
    uint32_t b = __float_as_uint(lo) + 0x8000u;
    return __builtin_amdgcn_perm(a, b, 0x07060302u); // bytes: a3 a2 b3 b2
}

// ---------------- Pre-kernel: w [512][1024] fp32 -> wt2 FRAGMENT layout -------------------
// wt2[kt=16][nt=64][lane=64][e=8] bf16: element (kt,nt,lane,e) = Wt[n][k] = w[k][n] with
// n = nt*16 + (lane&15), k = kt*32 + (lane>>4)*8 + e. A wave's A-fragment (nt,kt) is then
// ONE coalesced 1 KB read at base + lane*16B (full-line L2 bursts; no strided waste).
__global__ __launch_bounds__(256) void wt_prep(const float* __restrict__ w,
                                               uint16_t* __restrict__ wt2) {
    int g = blockIdx.x * 256 + threadIdx.x;   // 65536 threads
    int lane = g & 63;
    int nt   = (g >> 6) & 63;
    int kt   = g >> 12;
    int n  = nt * 16 + (lane & 15);
    int k0 = kt * 32 + (lane >> 4) * 8;
    const float* p = w + (size_t)k0 * 1024 + n;
    float f[8];
#pragma unroll
    for (int e = 0; e < 8; ++e) f[e] = p[(size_t)e * 1024];
    u32x4 pk;
    pk.x = pack_rnd(f[0], f[1]);
    pk.y = pack_rnd(f[2], f[3]);
    pk.z = pack_rnd(f[4], f[5]);
    pk.w = pack_rnd(f[6], f[7]);
    *(u32x4*)(wt2 + (size_t)g * 8) = pk;
}

// ---------------- Main kernel -------------------------------------------------------------
// v8: X-resident (128-pixel m-strip, full K=512 panel in 128 KB LDS, staged once) +
// W A-fragments loaded DIRECTLY to registers from the pre-fragmented wt2 (coalesced 1 KB
// bursts, L2-hot), 1-step reg double-buffer. ZERO barriers after X staging: waves desync
// and hide their own latency. 4x4 acc blocking, 64 k32-steps. nb order staggered by blk&3
// to spread epilogue write bursts + W L2 reads. 512 thr (8 waves), 1 block/CU.
__global__ __launch_bounds__(512, 2) void tconv_gemm(const float* __restrict__ x,
                                                     const uint16_t* __restrict__ wt2,
                                                     const float* __restrict__ bias,
                                                     float* __restrict__ out) {
    extern __shared__ uint16_t lds[]; // 128 KB: X panel [kt64=8][m=128][chunk8 swizzled]

    const int tid  = threadIdx.x;
    const int l    = tid & 63;
    const int wv   = tid >> 6;      // 0..7
    const int l15  = l & 15;
    const int quad = l >> 4;

    const int blk = blockIdx.x;     // 0..255
    const int b   = blk >> 5;       // batch
    const int p0  = (blk & 31) * 128;
    const float* xblk = x + (size_t)b * 512 * 4096 + p0;

    // ---- X staging constants: thread covers 4m x 8k per round, 4 rounds of 128 k ----
    const int mq4 = (tid & 31) * 4;
    const int ko  = tid >> 5;                 // 0..15 (k-octet within round)
    const float* xsrc = xblk + (size_t)(ko * 8) * 4096 + mq4;
    int xw0[4];
#pragma unroll
    for (int mm = 0; mm < 4; ++mm) {
        int m = mq4 + mm;
        xw0[mm] = (ko >> 3) * 8192 + m * 64 + (((ko & 7) ^ ((m >> 1) & 7)) << 3);
    }

#define PACKW(VB, DST)                                                    \
    {                                                                     \
        _Pragma("unroll")                                                 \
        for (int mm = 0; mm < 4; ++mm) {                                  \
            u32x4 pk;                                                     \
            pk.x = pack_rnd(VB[0][mm], VB[1][mm]);                        \
            pk.y = pack_rnd(VB[2][mm], VB[3][mm]);                        \
            pk.z = pack_rnd(VB[4][mm], VB[5][mm]);                        \
            pk.w = pack_rnd(VB[6][mm], VB[7][mm]);                        \
            *(u32x4*)(lds + xw0[mm] + (DST)) = pk;                        \
        }                                                                 \
    }

    // ---- stage X panel (once) ----
    {
        f32x4 va[8], vb[8];
#pragma unroll
        for (int r = 0; r < 8; ++r) va[r] = *(const f32x4*)(xsrc + (size_t)r * 4096);
        const float* x1 = xsrc + (size_t)128 * 4096;
#pragma unroll
        for (int r = 0; r < 8; ++r) vb[r] = *(const f32x4*)(x1 + (size_t)r * 4096);
        PACKW(va, 0)
        const float* x2 = xsrc + (size_t)256 * 4096;
#pragma unroll
        for (int r = 0; r < 8; ++r) va[r] = *(const f32x4*)(x2 + (size_t)r * 4096);
        PACKW(vb, 16384)
        const float* x3 = xsrc + (size_t)384 * 4096;
#pragma unroll
        for (int r = 0; r < 8; ++r) vb[r] = *(const f32x4*)(x3 + (size_t)r * 4096);
        PACKW(va, 32768)
        PACKW(vb, 49152)
    }

    // ---- W fragment pointer: wave pair (wv>>1) owns a 64-n slice; lane offset l*16B ----
    // elem offset(nbv, kt, tn) = (kt*64 + nbv*16 + (wv>>1)*4 + tn) * 512 + l*8
    const uint16_t* wlane = wt2 + (size_t)((wv >> 1) * 4) * 512 + l * 8;
    const int s = blk & 3;                    // nb stagger

    // prologue A-frags (nbv=s, kt=0) -- issued before the barrier, stay in flight across it
    bf16x8 afc[4];
#pragma unroll
    for (int tn = 0; tn < 4; ++tn)
        afc[tn] = *(const bf16x8*)(wlane + (size_t)s * 8192 + tn * 512);

    // the ONLY barrier: X ds_writes visible (lgkm); X f32 loads already consumed by packs;
    // afc reg-loads intentionally NOT drained (raw barrier, no vmcnt).
    asm volatile("s_waitcnt lgkmcnt(0)" ::: "memory");
    __builtin_amdgcn_sched_barrier(0);
    __builtin_amdgcn_s_barrier();
    __builtin_amdgcn_sched_barrier(0);

    // ---- B-fragment (X) LDS read offsets ----
    const int wave_m = (wv & 1) * 64;
    int boff[2][4];
#pragma unroll
    for (int p = 0; p < 2; ++p)
#pragma unroll
        for (int tm = 0; tm < 4; ++tm) {
            int m = wave_m + tm * 16 + l15;
            boff[p][tm] = m * 64 + (((p * 4 + quad) ^ ((m >> 1) & 7)) << 3);
        }

    f32x4 acc[4][4];
#pragma unroll
    for (int tn = 0; tn < 4; ++tn)
#pragma unroll
        for (int tm = 0; tm < 4; ++tm) acc[tn][tm] = f32x4{0.f, 0.f, 0.f, 0.f};

    const int y_base = (blk & 31) * 4;
    float* outb = out + (size_t)b * 256 * 16384;
    const int obase0 = (wv >> 1) * 16 + quad;

    // ---- main: 4 n-tiles x 16 k32-steps, NO barriers, reg double-buffered A-frags ----
    for (int nb = 0; nb < 4; ++nb) {
        const int nbv = (nb + s) & 3;
        const size_t wnb      = (size_t)nbv * 8192;            // nbv*16*512
        const size_t wnb_next = (size_t)((nbv + 1) & 3) * 8192;
#pragma unroll
        for (int t = 0; t < 16; ++t) {
            // prefetch next step's A-frags (kt=t+1, or next nbv's kt=0)
            bf16x8 afn[4];
            const bool pf = (nb < 3) || (t < 15);
            if (pf) {
                const uint16_t* wp = wlane + ((t < 15) ? (wnb + (size_t)(t + 1) * 32768)
                                                       : wnb_next);
#pragma unroll
                for (int tn = 0; tn < 4; ++tn)
                    afn[tn] = *(const bf16x8*)(wp + tn * 512);
            }

            // B frags + 16 MFMAs (afc loaded one full step ago -> L2 latency hidden)
            const int bbase = (t >> 1) * 8192;
            bf16x8 bf[4];
#pragma unroll
            for (int tm = 0; tm < 4; ++tm)
                bf[tm] = *(const bf16x8*)(lds + bbase + boff[t & 1][tm]);
#pragma unroll
            for (int tn = 0; tn < 4; ++tn)
#pragma unroll
                for (int tm = 0; tm < 4; ++tm)
                    acc[tn][tm] = __builtin_amdgcn_mfma_f32_16x16x32_bf16(
                        afc[tn], bf[tm], acc[tn][tm], 0, 0, 0);

            if (pf) {
#pragma unroll
                for (int tn = 0; tn < 4; ++tn) afc[tn] = afn[tn];
            }
        }

        // ---- epilogue for this n-tile: o = nbv*64 + obase0 + tn*4; regs = (i,j) 2x2 ----
#pragma unroll
        for (int tn = 0; tn < 4; ++tn) {
            int o = nbv * 64 + obase0 + tn * 4;
            float bv = bias[o];
#pragma unroll
            for (int tm = 0; tm < 4; ++tm) {
                int loc = wave_m + tm * 16 + l15;
                int hl  = loc >> 6;
                int ww  = loc & 63;
                float* p = outb + ((size_t)(o * 128 + y_base + 2 * hl)) * 128 + 2 * ww;
                f32x4 a = acc[tn][tm];
                float2 t0; t0.x = a.x + bv; t0.y = a.y + bv;   // (i=0, j=0,1)
                float2 t1; t1.x = a.z + bv; t1.y = a.w + bv;   // (i=1, j=0,1)
                *(float2*)(p)       = t0;
                *(float2*)(p + 128) = t1;
                acc[tn][tm] = f32x4{0.f, 0.f, 0.f, 0.f};
            }
        }
    }
#undef PACKW
}

extern "C" void kernel_launch(void* const* d_in, const int* in_sizes, int n_in,
                              void* d_out, int out_size, void* d_ws, size_t ws_size,
                              hipStream_t stream) {
    const float* x    = (const float*)d_in[0];  // [8][512][64][64]
    const float* w    = (const float*)d_in[1];  // [512][256][2][2] = [512][1024]
    const float* bias = (const float*)d_in[2];  // [256]
    float* out        = (float*)d_out;          // [8][256][128][128]
    uint16_t* wt2     = (uint16_t*)d_ws;        // fragment-layout Wt (1 MiB)

    // 128 KB dynamic LDS (X panel only); gfx950 allows up to 160 KB/workgroup.
    hipFuncSetAttribute((const void*)tconv_gemm,
                        hipFuncAttributeMaxDynamicSharedMemorySize, 131072);

    wt_prep<<<256, 256, 0, stream>>>(w, wt2);
    tconv_gemm<<<256, 512, 131072, stream>>>(x, wt2, bias, out);
}

// Round 8
// 212.406 us; speedup vs baseline: 1.2202x; 1.2202x over previous
//
#include <hip/hip_runtime.h>
#include <stdint.h>

#define AS1 __attribute__((address_space(1)))
#define AS3 __attribute__((address_space(3)))

typedef float   f32x4  __attribute__((ext_vector_type(4)));
typedef __bf16  bf16x8 __attribute__((ext_vector_type(8)));
typedef uint32_t u32x4 __attribute__((ext_vector_type(4)));

// Round-half-up fp32->bf16 for a pair, packed into one dword: low16 = lo, high16 = hi.
__device__ __forceinline__ uint32_t pack_rnd(float lo, float hi) {
    uint32_t a = __float_as_uint(hi) + 0x8000u;
    uint32_t b = __float_as_uint(lo) + 0x8000u;
    return __builtin_amdgcn_perm(a, b, 0x07060302u); // bytes: a3 a2 b3 b2
}

// ---------------- Pre-kernel: weight [512][1024] fp32 -> Wt [1024][512] bf16 --------------
__global__ __launch_bounds__(256) void wt_prep(const float* __restrict__ w,
                                               uint16_t* __restrict__ wt) {
    int t = blockIdx.x * 256 + threadIdx.x;   // 131072 threads
    int n = t & 1023;
    int c = (t >> 10) << 2;                   // c-quad base, 0..508
    const float* p = w + (size_t)c * 1024 + n;
    float f0 = p[0], f1 = p[1024], f2 = p[2048], f3 = p[3072];
    uint2 r;
    r.x = pack_rnd(f0, f1);
    r.y = pack_rnd(f2, f3);
    *(uint2*)(wt + (size_t)n * 512 + c) = r;
}

// ---------------- Main kernel -------------------------------------------------------------
// v9 = v6 (X-resident, W gll ring, proven best ~70us) with HALVED barrier count:
// phase = {stage W tiles t+2,t+3 -> compute steps t,t+1 -> vmcnt(0)+barrier}. Ring 4-deep
// permits staging 2 ahead while computing 2; glls get ~1240cyc compute shadow (>> L2 ~400).
// Plus s_setprio(1/0) around each 8-MFMA cluster (T5: phases give waves role diversity).
// 512 thr (8 waves), LDS = 128 KB X + 32 KB ring = 160 KB, 1 block/CU, grid=256.
__global__ __launch_bounds__(512, 2) void tconv_gemm(const float* __restrict__ x,
                                                     const uint16_t* __restrict__ wt,
                                                     const float* __restrict__ bias,
                                                     float* __restrict__ out) {
    extern __shared__ uint16_t lds[]; // [0,65536): X panel; [65536,81920): W ring 4x4096

    const int tid  = threadIdx.x;
    const int l    = tid & 63;
    const int wv   = tid >> 6;      // 0..7
    const int l15  = l & 15;
    const int quad = l >> 4;

    const int blk = blockIdx.x;     // 0..255
    const int b   = blk >> 5;       // batch
    const int p0  = (blk & 31) * 128;
    const float* xblk = x + (size_t)b * 512 * 4096 + p0;

    // ---- X staging constants: thread covers 4m x 8k per round, 4 rounds of 128 k ----
    const int mq4 = (tid & 31) * 4;
    const int ko  = tid >> 5;                 // 0..15 (k-octet within round)
    const float* xsrc = xblk + (size_t)(ko * 8) * 4096 + mq4;
    int xw0[4];
#pragma unroll
    for (int mm = 0; mm < 4; ++mm) {
        int m = mq4 + mm;
        xw0[mm] = (ko >> 3) * 8192 + m * 64 + (((ko & 7) ^ ((m >> 1) & 7)) << 3);
    }

    // ---- W gll constants: wave stages rows [wv*16, wv*16+16) of each [128][32] tile ----
    const int rr = l >> 2, cc = l & 3;
    const int R  = wv * 16 + rr;              // row within tile
    const uint16_t* wbase = wt + R * 512 + ((cc ^ ((R >> 1) & 3)) << 3); // pre-swizzled src

    // ---- fragment offsets ----
    const int wave_n = (wv >> 2) * 64;        // {0,64}
    const int wave_m = (wv & 3) * 32;         // {0,32,64,96}
    int aoff[4];
#pragma unroll
    for (int tn = 0; tn < 4; ++tn) {
        int n = wave_n + tn * 16 + l15;
        aoff[tn] = 65536 + n * 32 + ((quad ^ ((n >> 1) & 3)) << 3);
    }
    int boff[2][2];
#pragma unroll
    for (int p = 0; p < 2; ++p)
#pragma unroll
        for (int tm = 0; tm < 2; ++tm) {
            int m = wave_m + tm * 16 + l15;
            boff[p][tm] = m * 64 + (((p * 4 + quad) ^ ((m >> 1) & 7)) << 3);
        }

#define PACKW(VB, DST)                                                    \
    {                                                                     \
        _Pragma("unroll")                                                 \
        for (int mm = 0; mm < 4; ++mm) {                                  \
            u32x4 pk;                                                     \
            pk.x = pack_rnd(VB[0][mm], VB[1][mm]);                        \
            pk.y = pack_rnd(VB[2][mm], VB[3][mm]);                        \
            pk.z = pack_rnd(VB[4][mm], VB[5][mm]);                        \
            pk.w = pack_rnd(VB[6][mm], VB[7][mm]);                        \
            *(u32x4*)(lds + xw0[mm] + (DST)) = pk;                        \
        }                                                                 \
    }

    // ---- stage X panel (once) + W tiles 0,1 into ring slots 0,1 ----
    {
        f32x4 va[8], vb[8];
#pragma unroll
        for (int r = 0; r < 8; ++r) va[r] = *(const f32x4*)(xsrc + (size_t)r * 4096);
        const float* x1 = xsrc + (size_t)128 * 4096;
#pragma unroll
        for (int r = 0; r < 8; ++r) vb[r] = *(const f32x4*)(x1 + (size_t)r * 4096);
        PACKW(va, 0)
        const float* x2 = xsrc + (size_t)256 * 4096;
#pragma unroll
        for (int r = 0; r < 8; ++r) va[r] = *(const f32x4*)(x2 + (size_t)r * 4096);
        PACKW(vb, 16384)
        const float* x3 = xsrc + (size_t)384 * 4096;
#pragma unroll
        for (int r = 0; r < 8; ++r) vb[r] = *(const f32x4*)(x3 + (size_t)r * 4096);
        // W tiles 0,1 (newest in queue; X loads above get consumed by the packs)
#pragma unroll
        for (int u = 0; u < 2; ++u)
            __builtin_amdgcn_global_load_lds((AS1 void*)(wbase + u * 32),
                                             (AS3 void*)(lds + 65536 + u * 4096 + wv * 512),
                                             16, 0, 0);
        PACKW(va, 32768)
        PACKW(vb, 49152)
    }
    asm volatile("s_waitcnt vmcnt(0) lgkmcnt(0)" ::: "memory"); // X visible + W(0),W(1) landed
    __builtin_amdgcn_sched_barrier(0);
    __builtin_amdgcn_s_barrier();
    __builtin_amdgcn_sched_barrier(0);

    f32x4 acc[4][2];
#pragma unroll
    for (int tn = 0; tn < 4; ++tn)
#pragma unroll
        for (int tm = 0; tm < 2; ++tm) acc[tn][tm] = f32x4{0.f, 0.f, 0.f, 0.f};

    const int y_base = (blk & 31) * 4;
    float* outb = out + (size_t)b * 256 * 16384;
    const int obase0 = (wv >> 2) * 16 + quad;

#define STEP_BODY(T)                                                                   \
    {                                                                                  \
        bf16x8 af[4], bq[2];                                                           \
        _Pragma("unroll")                                                              \
        for (int tn = 0; tn < 4; ++tn)                                                 \
            af[tn] = *(const bf16x8*)(lds + ((T) & 3) * 4096 + aoff[tn]);              \
        _Pragma("unroll")                                                              \
        for (int tm = 0; tm < 2; ++tm)                                                 \
            bq[tm] = *(const bf16x8*)(lds + ((T) >> 1) * 8192 + boff[(T) & 1][tm]);    \
        __builtin_amdgcn_s_setprio(1);                                                 \
        _Pragma("unroll")                                                              \
        for (int tn = 0; tn < 4; ++tn)                                                 \
            _Pragma("unroll")                                                          \
            for (int tm = 0; tm < 2; ++tm)                                             \
                acc[tn][tm] = __builtin_amdgcn_mfma_f32_16x16x32_bf16(                 \
                    af[tn], bq[tm], acc[tn][tm], 0, 0, 0);                             \
        __builtin_amdgcn_s_setprio(0);                                                 \
    }

#define EPILOGUE(NB)                                                                   \
    {                                                                                  \
        _Pragma("unroll")                                                              \
        for (int tn = 0; tn < 4; ++tn) {                                               \
            int o = (NB) * 32 + obase0 + tn * 4;                                       \
            float bv = bias[o];                                                        \
            _Pragma("unroll")                                                          \
            for (int tm = 0; tm < 2; ++tm) {                                           \
                int loc = wave_m + tm * 16 + l15;                                      \
                int hl  = loc >> 6;                                                    \
                int ww  = loc & 63;                                                    \
                float* p = outb + ((size_t)(o * 128 + y_base + 2 * hl)) * 128 + 2 * ww;\
                f32x4 a = acc[tn][tm];                                                 \
                float2 t0; t0.x = a.x + bv; t0.y = a.y + bv;                           \
                float2 t1; t1.x = a.z + bv; t1.y = a.w + bv;                           \
                *(float2*)(p)       = t0;                                              \
                *(float2*)(p + 128) = t1;                                              \
                acc[tn][tm] = f32x4{0.f, 0.f, 0.f, 0.f};                               \
            }                                                                          \
        }                                                                              \
    }

    // ---- main: 8 n-tiles x 8 phases; phase = stage(t+2,t+3) + compute(t,t+1) + barrier ----
    const uint16_t* wcur = wbase;           // + nb*65536
    for (int nb = 0; nb < 8; ++nb) {
#pragma unroll
        for (int p = 0; p < 8; ++p) {
            // stage W tiles u = 2p+2, 2p+3 into slots u&3 (u>=16 wraps into next n-tile)
            if (nb < 7 || p < 7) {
#pragma unroll
                for (int q = 0; q < 2; ++q) {
                    const int u = 2 * p + 2 + q;
                    const uint16_t* wsrc = (u < 16) ? (wcur + u * 32)
                                                    : (wcur + 65536 + (u - 16) * 32);
                    __builtin_amdgcn_global_load_lds((AS1 void*)wsrc,
                        (AS3 void*)(lds + 65536 + (u & 3) * 4096 + wv * 512), 16, 0, 0);
                }
            }

            STEP_BODY(2 * p)
            STEP_BODY(2 * p + 1)

            // phase end: glls landed (~1240cyc shadow, L2-hot) + my ds_reads done
            if (!(nb == 7 && p == 7)) {
                asm volatile("s_waitcnt vmcnt(0) lgkmcnt(0)" ::: "memory");
                __builtin_amdgcn_sched_barrier(0);
                __builtin_amdgcn_s_barrier();
                __builtin_amdgcn_sched_barrier(0);
            }
        }
        EPILOGUE(nb)
        wcur += 65536;
    }
#undef STEP_BODY
#undef EPILOGUE
#undef PACKW
}

extern "C" void kernel_launch(void* const* d_in, const int* in_sizes, int n_in,
                              void* d_out, int out_size, void* d_ws, size_t ws_size,
                              hipStream_t stream) {
    const float* x    = (const float*)d_in[0];  // [8][512][64][64]
    const float* w    = (const float*)d_in[1];  // [512][256][2][2] = [512][1024]
    const float* bias = (const float*)d_in[2];  // [256]
    float* out        = (float*)d_out;          // [8][256][128][128]
    uint16_t* wt      = (uint16_t*)d_ws;        // [1024][512] bf16 (1 MiB)

    // 160 KB dynamic LDS (X 128 KB + W ring 32 KB); gfx950 allows 160 KB/workgroup.
    hipFuncSetAttribute((const void*)tconv_gemm,
                        hipFuncAttributeMaxDynamicSharedMemorySize, 163840);

    wt_prep<<<512, 256, 0, stream>>>(w, wt);
    tconv_gemm<<<256, 512, 163840, stream>>>(x, wt, bias, out);
}